// Round 1
// baseline (253.470 us; speedup 1.0000x reference)
//
#include <hip/hip_runtime.h>

static constexpr int N = 128;
static constexpr int F = 128;
static constexpr int H = 8;
static constexpr int NATTR = 3;
static constexpr int M = N * N;        // 16384
static constexpr int OUTW = 320;       // F + 8*16 + 8*8

__device__ __forceinline__ float leaky(float x) { return x >= 0.f ? x : 0.2f * x; }

// ---------------------------------------------------------------------------
// out[:, a, 0:128] = X  for all attrs
__global__ void k_copy_x(const float* __restrict__ X, float* __restrict__ out) {
    int idx = blockIdx.x * 256 + threadIdx.x;            // 3*128*128 total
    if (idx >= NATTR * N * F) return;
    int f = idx % F;
    int rest = idx / F;
    int a = rest % NATTR;
    int n = rest / NATTR;
    out[(n * NATTR + a) * OUTW + f] = X[n * F + f];
}

// ---------------------------------------------------------------------------
// Layer-0 edge features (attr-independent): fe0[h][m][4], ae0[h][m]
__global__ void k_feat_e0(const float* __restrict__ E,     // [3][N][N]
                          const float* __restrict__ We0,   // [8][3][4]
                          const float* __restrict__ ae0n,  // [8][4]
                          float* __restrict__ fe0,         // [8][M][4]
                          float* __restrict__ ae0) {       // [8][M]
    int m = blockIdx.x * 256 + threadIdx.x;
    if (m >= M) return;
    float e0 = E[m], e1 = E[M + m], e2 = E[2 * M + m];
    for (int h = 0; h < H; ++h) {
        float4 v;
        float* vp = &v.x;
        float aa = 0.f;
        for (int ke = 0; ke < 4; ++ke) {
            float f = e0 * We0[(h * 3 + 0) * 4 + ke] +
                      e1 * We0[(h * 3 + 1) * 4 + ke] +
                      e2 * We0[(h * 3 + 2) * 4 + ke];
            vp[ke] = f;
            aa += f * ae0n[h * 4 + ke];
        }
        *(float4*)&fe0[(size_t)(h * M + m) * 4] = v;
        ae0[h * M + m] = aa;
    }
}

// Layer-1 edge features (attr-independent): fe1[h][m][2], ae1[h][m]
__global__ void k_feat_e1(const float* __restrict__ fe0,   // [8][M][4]
                          const float* __restrict__ We1,   // [8][32][2]
                          const float* __restrict__ ae1n,  // [8][2]
                          float* __restrict__ fe1,         // [8][M][2]
                          float* __restrict__ ae1) {       // [8][M]
    __shared__ float sW[8 * 32 * 2];
    for (int i = threadIdx.x; i < 512; i += 256) sW[i] = We1[i];
    __syncthreads();
    int m = blockIdx.x * 256 + threadIdx.x;
    if (m >= M) return;
    float xe[32];
    for (int hp = 0; hp < 8; ++hp) {
        float4 v = *(const float4*)&fe0[(size_t)(hp * M + m) * 4];
        xe[hp * 4 + 0] = v.x; xe[hp * 4 + 1] = v.y;
        xe[hp * 4 + 2] = v.z; xe[hp * 4 + 3] = v.w;
    }
    for (int h = 0; h < H; ++h) {
        float f0 = 0.f, f1 = 0.f;
        for (int c = 0; c < 32; ++c) {
            f0 += xe[c] * sW[(h * 32 + c) * 2 + 0];
            f1 += xe[c] * sW[(h * 32 + c) * 2 + 1];
        }
        *(float2*)&fe1[(size_t)(h * M + m) * 2] = make_float2(f0, f1);
        ae1[h * M + m] = f0 * ae1n[h * 2 + 0] + f1 * ae1n[h * 2 + 1];
    }
}

// ---------------------------------------------------------------------------
// Node features: feat[a][h][n][k] (stride 16), a_self[a][h][n]
template <int K>
__global__ void k_feat(const float* __restrict__ Xsrc, int aStride,
                       const float* __restrict__ Wn,    // [3][8][F][K]
                       const float* __restrict__ aes,   // [8][K]  (ae*_s)
                       float* __restrict__ feat,        // [3][8][N][16]
                       float* __restrict__ a_self) {    // [3][8][N]
    int a = blockIdx.x / H, h = blockIdx.x % H;
    const float* Xp = Xsrc + (size_t)a * aStride;
    const float* Wp = Wn + (size_t)(a * H + h) * F * K;
    __shared__ float sW[F * K];
    __shared__ float sF[N * K];
    for (int i = threadIdx.x; i < F * K; i += 256) sW[i] = Wp[i];
    __syncthreads();
    for (int o = threadIdx.x; o < N * K; o += 256) {
        int n = o / K, k = o % K;
        const float* xr = Xp + n * F;
        float acc = 0.f;
        for (int f = 0; f < F; ++f) acc += xr[f] * sW[f * K + k];
        sF[o] = acc;
        feat[((a * H + h) * N + n) * 16 + k] = acc;
    }
    __syncthreads();
    for (int n = threadIdx.x; n < N; n += 256) {
        float acc = 0.f;
        for (int k = 0; k < K; ++k) acc += sF[n * K + k] * aes[h * K + k];
        a_self[(a * H + h) * N + n] = acc;
    }
}

// ---------------------------------------------------------------------------
// Edge-to-node attention: one block per (a,h,n); online softmax over M.
template <int KE>
__global__ void __launch_bounds__(256)
k_edge_attn(const float* __restrict__ fe,      // [8][M][KE]
            const float* __restrict__ ae,      // [8][M]
            const float* __restrict__ a_self,  // [3][8][N]
            const float* __restrict__ adj,     // [N][M]
            const float* __restrict__ be,      // [8][KE]
            float* __restrict__ nfe) {         // [3][8][N][4]
    int b = blockIdx.x;
    int n = b & (N - 1);
    int h = (b >> 7) & (H - 1);
    int a = b >> 10;
    int tid = threadIdx.x;
    float as = a_self[(a * H + h) * N + n];
    const float* aep = ae + (size_t)h * M;
    const float* fep = fe + (size_t)h * M * KE;
    const float* adjp = adj + (size_t)n * M;

    float mx = -1e30f, sum = 0.f;
    float acc[KE];
#pragma unroll
    for (int k = 0; k < KE; ++k) acc[k] = 0.f;

    for (int m = tid; m < M; m += 256) {
        float v = as + aep[m];
        v = (v >= 0.f) ? v : 0.2f * v;
        v += adjp[m];
        if (v > mx) {
            float r = __expf(mx - v);
            sum *= r;
#pragma unroll
            for (int k = 0; k < KE; ++k) acc[k] *= r;
            mx = v;
        }
        float p = __expf(v - mx);
        sum += p;
        if (KE == 4) {
            const float4 f = *(const float4*)(fep + (size_t)m * 4);
            acc[0] += p * f.x; acc[1] += p * f.y;
            acc[2] += p * f.z; acc[3] += p * f.w;
        } else {
            const float2 f = *(const float2*)(fep + (size_t)m * 2);
            acc[0] += p * f.x; acc[1] += p * f.y;
        }
    }

    __shared__ float red[256];
    red[tid] = mx; __syncthreads();
    for (int s = 128; s > 0; s >>= 1) {
        if (tid < s) red[tid] = fmaxf(red[tid], red[tid + s]);
        __syncthreads();
    }
    float gmx = red[0]; __syncthreads();
    float sc = __expf(mx - gmx);
    sum *= sc;
#pragma unroll
    for (int k = 0; k < KE; ++k) acc[k] *= sc;

    red[tid] = sum; __syncthreads();
    for (int s = 128; s > 0; s >>= 1) {
        if (tid < s) red[tid] += red[tid + s];
        __syncthreads();
    }
    float gsum = red[0]; __syncthreads();

    float res[KE];
#pragma unroll
    for (int k = 0; k < KE; ++k) {
        red[tid] = acc[k]; __syncthreads();
        for (int s = 128; s > 0; s >>= 1) {
            if (tid < s) red[tid] += red[tid + s];
            __syncthreads();
        }
        if (tid == 0) res[k] = red[0];
        __syncthreads();
    }
    if (tid == 0) {
#pragma unroll
        for (int k = 0; k < KE; ++k)
            nfe[((a * H + h) * N + n) * 4 + k] = res[k] / gsum + be[h * KE + k];
    }
}

// ---------------------------------------------------------------------------
// feat2 = [feat|nfe] @ Wct + bct; s2 = feat2·an_s; n2 = feat2·an_n
template <int K, int KE>
__global__ void k_feat2(const float* __restrict__ feat,   // [3][8][N][16]
                        const float* __restrict__ nfe,    // [3][8][N][4]
                        const float* __restrict__ Wct,    // [8][K+KE][K]
                        const float* __restrict__ bct,    // [8][K]
                        const float* __restrict__ ans,    // [3][8][K]
                        const float* __restrict__ ann,    // [3][8][K]
                        float* __restrict__ feat2,        // [3][8][N][16]
                        float* __restrict__ s2,           // [3][8][N]
                        float* __restrict__ n2) {         // [3][8][N]
    constexpr int CIN = K + KE;
    int a = blockIdx.x / H, h = blockIdx.x % H;
    __shared__ float sW[CIN * K];
    __shared__ float sIn[N * CIN];
    __shared__ float sOut[N * K];
    for (int i = threadIdx.x; i < CIN * K; i += 256) sW[i] = Wct[h * CIN * K + i];
    for (int i = threadIdx.x; i < N * K; i += 256) {
        int n = i / K, k = i % K;
        sIn[n * CIN + k] = feat[((a * H + h) * N + n) * 16 + k];
    }
    for (int i = threadIdx.x; i < N * KE; i += 256) {
        int n = i / KE, k = i % KE;
        sIn[n * CIN + K + k] = nfe[((a * H + h) * N + n) * 4 + k];
    }
    __syncthreads();
    for (int o = threadIdx.x; o < N * K; o += 256) {
        int n = o / K, k = o % K;
        float acc = bct[h * K + k];
        for (int c = 0; c < CIN; ++c) acc += sIn[n * CIN + c] * sW[c * K + k];
        sOut[o] = acc;
        feat2[((a * H + h) * N + n) * 16 + k] = acc;
    }
    __syncthreads();
    for (int n = threadIdx.x; n < N; n += 256) {
        float ss = 0.f, nn = 0.f;
        for (int k = 0; k < K; ++k) {
            ss += sOut[n * K + k] * ans[(a * H + h) * K + k];
            nn += sOut[n * K + k] * ann[(a * H + h) * K + k];
        }
        s2[(a * H + h) * N + n] = ss;
        n2[(a * H + h) * N + n] = nn;
    }
}

// ---------------------------------------------------------------------------
// c[a][m] = colsum(E_info); d[a][h][m] = n2[a][h]·E_info[:,m]
__global__ void k_cd(const float* __restrict__ Einfo,  // [3][N][N]
                     const float* __restrict__ n2,     // [3][8][N]
                     float* __restrict__ cE,           // [3][N]
                     float* __restrict__ dE) {         // [3][8][N]
    int a = blockIdx.x;
    int m = threadIdx.x;  // 128 threads
    __shared__ float sn2[H * N];
    for (int i = threadIdx.x; i < H * N; i += 128) sn2[i] = n2[a * H * N + i];
    __syncthreads();
    const float* Ep = Einfo + (size_t)a * N * N;
    float c = 0.f, dacc[H];
#pragma unroll
    for (int h = 0; h < H; ++h) dacc[h] = 0.f;
    for (int j = 0; j < N; ++j) {
        float v = Ep[j * N + m];
        c += v;
#pragma unroll
        for (int h = 0; h < H; ++h) dacc[h] += sn2[h * N + j] * v;
    }
    cE[a * N + m] = c;
#pragma unroll
    for (int h = 0; h < H; ++h) dE[(a * H + h) * N + m] = dacc[h];
}

// ---------------------------------------------------------------------------
// Node attention + elu + output write. One block per (a,h,i), 128 threads.
template <int K>
__global__ void __launch_bounds__(128)
k_node_attn(const float* __restrict__ feat2,   // [3][8][N][16]
            const float* __restrict__ s2,      // [3][8][N]
            const float* __restrict__ cE,      // [3][N]
            const float* __restrict__ dE,      // [3][8][N]
            const float* __restrict__ Amat,    // [3][N][N]
            const float* __restrict__ bn,      // [3][8][K]
            float* __restrict__ out, int outOff,
            float* __restrict__ Xh,            // [3][N][128] or nullptr
            float* __restrict__ EinfoNext) {   // [3][N][N] or nullptr
    int b = blockIdx.x;
    int i = b & (N - 1);
    int h = (b >> 7) & (H - 1);
    int a = b >> 10;
    int m = threadIdx.x;

    float s = s2[(a * H + h) * N + i];
    float v = leaky(s * cE[a * N + m] + dE[(a * H + h) * N + m]) +
              Amat[(a * N + i) * N + m];

    __shared__ float red[N];
    __shared__ float salpha[N];
    red[m] = v; __syncthreads();
    for (int st = 64; st > 0; st >>= 1) {
        if (m < st) red[m] = fmaxf(red[m], red[m + st]);
        __syncthreads();
    }
    float gmx = red[0]; __syncthreads();
    float p = __expf(v - gmx);
    red[m] = p; __syncthreads();
    for (int st = 64; st > 0; st >>= 1) {
        if (m < st) red[m] += red[m + st];
        __syncthreads();
    }
    float gsum = red[0]; __syncthreads();
    float alpha = p / gsum;
    salpha[m] = alpha;
    if (EinfoNext != nullptr && h == H - 1)
        EinfoNext[(a * N + i) * N + m] = alpha;
    __syncthreads();

    if (m < K) {
        float acc = bn[(a * H + h) * K + m];
        for (int mm = 0; mm < N; ++mm)
            acc += salpha[mm] * feat2[((a * H + h) * N + mm) * 16 + m];
        float e = acc > 0.f ? acc : __expf(acc) - 1.f;  // elu
        out[(i * NATTR + a) * OUTW + outOff + h * K + m] = e;
        if (Xh != nullptr) Xh[(a * N + i) * F + h * K + m] = e;
    }
}

// ---------------------------------------------------------------------------
extern "C" void kernel_launch(void* const* d_in, const int* in_sizes, int n_in,
                              void* d_out, int out_size, void* d_ws, size_t ws_size,
                              hipStream_t stream) {
    const float* X    = (const float*)d_in[0];
    const float* A    = (const float*)d_in[1];
    const float* E    = (const float*)d_in[2];
    const float* adj  = (const float*)d_in[3];
    const float* Wn0  = (const float*)d_in[4];
    const float* bn0  = (const float*)d_in[5];
    const float* an0s = (const float*)d_in[6];
    const float* an0n = (const float*)d_in[7];
    const float* Wn1  = (const float*)d_in[8];
    const float* bn1  = (const float*)d_in[9];
    const float* an1s = (const float*)d_in[10];
    const float* an1n = (const float*)d_in[11];
    const float* We0  = (const float*)d_in[12];
    const float* be0  = (const float*)d_in[13];
    const float* We1  = (const float*)d_in[14];
    const float* be1  = (const float*)d_in[15];
    const float* Wct0 = (const float*)d_in[16];
    const float* bct0 = (const float*)d_in[17];
    const float* Wct1 = (const float*)d_in[18];
    const float* bct1 = (const float*)d_in[19];
    const float* ae0s = (const float*)d_in[20];
    const float* ae0n = (const float*)d_in[21];
    const float* ae1s = (const float*)d_in[22];
    const float* ae1n = (const float*)d_in[23];
    float* out = (float*)d_out;

    float* p = (float*)d_ws;
    float* feat  = p; p += NATTR * H * N * 16;
    float* aself = p; p += NATTR * H * N;
    float* fe0   = p; p += H * M * 4;
    float* ae0e  = p; p += H * M;
    float* fe1   = p; p += H * M * 2;
    float* ae1e  = p; p += H * M;
    float* nfe   = p; p += NATTR * H * N * 4;
    float* feat2 = p; p += NATTR * H * N * 16;
    float* s2b   = p; p += NATTR * H * N;
    float* n2b   = p; p += NATTR * H * N;
    float* cb    = p; p += NATTR * N;
    float* db    = p; p += NATTR * H * N;
    float* einfo = p; p += NATTR * N * N;
    float* xh    = p; p += NATTR * N * F;

    k_copy_x<<<dim3(192), dim3(256), 0, stream>>>(X, out);
    k_feat_e0<<<dim3(64), dim3(256), 0, stream>>>(E, We0, ae0n, fe0, ae0e);
    k_feat_e1<<<dim3(64), dim3(256), 0, stream>>>(fe0, We1, ae1n, fe1, ae1e);

    // ---- layer 0 ----
    k_feat<16><<<dim3(24), dim3(256), 0, stream>>>(X, 0, Wn0, ae0s, feat, aself);
    k_edge_attn<4><<<dim3(3072), dim3(256), 0, stream>>>(fe0, ae0e, aself, adj, be0, nfe);
    k_feat2<16, 4><<<dim3(24), dim3(256), 0, stream>>>(feat, nfe, Wct0, bct0, an0s, an0n,
                                                       feat2, s2b, n2b);
    k_cd<<<dim3(3), dim3(128), 0, stream>>>(E, n2b, cb, db);
    k_node_attn<16><<<dim3(3072), dim3(128), 0, stream>>>(feat2, s2b, cb, db, A, bn0,
                                                          out, F, xh, einfo);

    // ---- layer 1 ----
    k_feat<8><<<dim3(24), dim3(256), 0, stream>>>(xh, N * F, Wn1, ae1s, feat, aself);
    k_edge_attn<2><<<dim3(3072), dim3(256), 0, stream>>>(fe1, ae1e, aself, adj, be1, nfe);
    k_feat2<8, 2><<<dim3(24), dim3(256), 0, stream>>>(feat, nfe, Wct1, bct1, an1s, an1n,
                                                      feat2, s2b, n2b);
    k_cd<<<dim3(3), dim3(128), 0, stream>>>(einfo, n2b, cb, db);
    k_node_attn<8><<<dim3(3072), dim3(128), 0, stream>>>(feat2, s2b, cb, db, A, bn1,
                                                         out, F + 128, nullptr, nullptr);
}

// Round 2
// 143.452 us; speedup vs baseline: 1.7669x; 1.7669x over previous
//
#include <hip/hip_runtime.h>

static constexpr int N = 128;
static constexpr int F = 128;
static constexpr int H = 8;
static constexpr int NATTR = 3;
static constexpr int M = N * N;        // 16384
static constexpr int OUTW = 320;       // F + 8*16 + 8*8
static constexpr int MS = 8;           // m-splits in edge attention

__device__ __forceinline__ float leaky(float x) { return x >= 0.f ? x : 0.2f * x; }

// ---------------------------------------------------------------------------
// out[:, a, 0:128] = X  for all attrs
__global__ void k_copy_x(const float* __restrict__ X, float* __restrict__ out) {
    int idx = blockIdx.x * 256 + threadIdx.x;            // 3*128*128 total
    if (idx >= NATTR * N * F) return;
    int f = idx % F;
    int rest = idx / F;
    int a = rest % NATTR;
    int n = rest / NATTR;
    out[(n * NATTR + a) * OUTW + f] = X[n * F + f];
}

// ---------------------------------------------------------------------------
// Fused edge features for BOTH layers in one pass over E.
// fe1 = (E @ We0_flat) @ We1 = E @ Wcomb  (f32 assoc, error ~1e-7)
__global__ void k_feat_e(const float* __restrict__ E,     // [3][N][N]
                         const float* __restrict__ We0,   // [8][3][4]
                         const float* __restrict__ ae0n,  // [8][4]
                         const float* __restrict__ We1,   // [8][32][2]
                         const float* __restrict__ ae1n,  // [8][2]
                         float* __restrict__ fe0,         // [8][M][4]
                         float* __restrict__ ae0,         // [8][M]
                         float* __restrict__ fe1,         // [8][M][2]
                         float* __restrict__ ae1) {       // [8][M]
    __shared__ float sW0[8 * 3 * 4];
    __shared__ float sA0[8 * 4];
    __shared__ float sA1[8 * 2];
    __shared__ float sWc[8 * 3 * 2];   // combined [h2][attr][k2]
    if (threadIdx.x < 96) sW0[threadIdx.x] = We0[threadIdx.x];
    if (threadIdx.x < 32) sA0[threadIdx.x] = ae0n[threadIdx.x];
    if (threadIdx.x < 16) sA1[threadIdx.x] = ae1n[threadIdx.x];
    __syncthreads();
    if (threadIdx.x < 48) {
        int h2 = threadIdx.x / 6;
        int rem = threadIdx.x % 6;
        int at = rem >> 1, k2 = rem & 1;
        float acc = 0.f;
        for (int c = 0; c < 32; ++c)   // c = hp*4+kp
            acc += sW0[((c >> 2) * 3 + at) * 4 + (c & 3)] * We1[(h2 * 32 + c) * 2 + k2];
        sWc[(h2 * 3 + at) * 2 + k2] = acc;
    }
    __syncthreads();
    int m = blockIdx.x * 256 + threadIdx.x;
    if (m >= M) return;
    float e0 = E[m], e1 = E[M + m], e2 = E[2 * M + m];
    for (int h = 0; h < H; ++h) {
        float4 v;
        float* vp = &v.x;
        float aa = 0.f;
#pragma unroll
        for (int ke = 0; ke < 4; ++ke) {
            float f = e0 * sW0[(h * 3 + 0) * 4 + ke] +
                      e1 * sW0[(h * 3 + 1) * 4 + ke] +
                      e2 * sW0[(h * 3 + 2) * 4 + ke];
            vp[ke] = f;
            aa += f * sA0[h * 4 + ke];
        }
        *(float4*)&fe0[(size_t)(h * M + m) * 4] = v;
        ae0[h * M + m] = aa;
        float f0 = e0 * sWc[(h * 3 + 0) * 2 + 0] + e1 * sWc[(h * 3 + 1) * 2 + 0] +
                   e2 * sWc[(h * 3 + 2) * 2 + 0];
        float f1 = e0 * sWc[(h * 3 + 0) * 2 + 1] + e1 * sWc[(h * 3 + 1) * 2 + 1] +
                   e2 * sWc[(h * 3 + 2) * 2 + 1];
        *(float2*)&fe1[(size_t)(h * M + m) * 2] = make_float2(f0, f1);
        ae1[h * M + m] = f0 * sA1[h * 2 + 0] + f1 * sA1[h * 2 + 1];
    }
}

// ---------------------------------------------------------------------------
// Node features: feat[a][h][n][k] (stride 16), a_self[a][h][n]
template <int K>
__global__ void k_feat(const float* __restrict__ Xsrc, int aStride,
                       const float* __restrict__ Wn,    // [3][8][F][K]
                       const float* __restrict__ aes,   // [8][K]  (ae*_s)
                       float* __restrict__ feat,        // [3][8][N][16]
                       float* __restrict__ a_self) {    // [3][8][N]
    int a = blockIdx.x / H, h = blockIdx.x % H;
    const float* Xp = Xsrc + (size_t)a * aStride;
    const float* Wp = Wn + (size_t)(a * H + h) * F * K;
    __shared__ float sW[F * 16];
    __shared__ float sF[N * 16];
    for (int i = threadIdx.x; i < F * K; i += 256) sW[i] = Wp[i];
    __syncthreads();
    for (int o = threadIdx.x; o < N * K; o += 256) {
        int n = o / K, k = o % K;
        const float* xr = Xp + n * F;
        float acc = 0.f;
        for (int f = 0; f < F; ++f) acc += xr[f] * sW[f * K + k];
        sF[o] = acc;
        feat[((a * H + h) * N + n) * 16 + k] = acc;
    }
    __syncthreads();
    for (int n = threadIdx.x; n < N; n += 256) {
        float acc = 0.f;
        for (int k = 0; k < K; ++k) acc += sF[n * K + k] * aes[h * K + k];
        a_self[(a * H + h) * N + n] = acc;
    }
}

// ---------------------------------------------------------------------------
// Edge-to-node attention, restructured:
//   block = (h, n-tile of 16, m-chunk of M/MS). Covers ALL 3 attrs.
//   thread = (row r = tid>>4, lane l = tid&15); lane strides m by 64 (float4).
//   No online max (logits are O(1); f32 exp exact enough). Partials out.
template <int KE>
__global__ void __launch_bounds__(256)
k_edge_attn(const float* __restrict__ fe,      // [8][M][KE]
            const float* __restrict__ ae,      // [8][M]
            const float* __restrict__ a_self,  // [3][8][N]
            const float* __restrict__ adj,     // [N][M]
            float* __restrict__ part) {        // [MS][3][8][N][8]
    int b = blockIdx.x;                // ((h*8 + nt)*MS + ms)
    int ms = b & (MS - 1);
    int nt = (b >> 3) & 7;
    int h = b >> 6;
    int tid = threadIdx.x;
    int r = tid >> 4, l = tid & 15;
    int n = nt * 16 + r;

    float as0 = a_self[(0 * H + h) * N + n];
    float as1 = a_self[(1 * H + h) * N + n];
    float as2 = a_self[(2 * H + h) * N + n];

    constexpr int CH = M / MS;         // 2048
    int m0 = ms * CH;
    const float* adjp = adj + (size_t)n * M + m0;
    const float* aep = ae + (size_t)h * M + m0;
    const float* fep = fe + ((size_t)h * M + m0) * KE;

    float sum0 = 0.f, sum1 = 0.f, sum2 = 0.f;
    float acc0[KE], acc1[KE], acc2[KE];
#pragma unroll
    for (int k = 0; k < KE; ++k) { acc0[k] = 0.f; acc1[k] = 0.f; acc2[k] = 0.f; }

    for (int i = l * 4; i < CH; i += 64) {
        const float4 av = *(const float4*)(adjp + i);
        const float4 ev = *(const float4*)(aep + i);
        float fv[4][KE];
#pragma unroll
        for (int j = 0; j < 4; ++j)
#pragma unroll
            for (int k = 0; k < KE; ++k) fv[j][k] = fep[(i + j) * KE + k];
#pragma unroll
        for (int j = 0; j < 4; ++j) {
            float adjv = reinterpret_cast<const float*>(&av)[j];
            float aev = reinterpret_cast<const float*>(&ev)[j];
            float p0 = __expf(leaky(as0 + aev) + adjv);
            float p1 = __expf(leaky(as1 + aev) + adjv);
            float p2 = __expf(leaky(as2 + aev) + adjv);
            sum0 += p0; sum1 += p1; sum2 += p2;
#pragma unroll
            for (int k = 0; k < KE; ++k) {
                acc0[k] += p0 * fv[j][k];
                acc1[k] += p1 * fv[j][k];
                acc2[k] += p2 * fv[j][k];
            }
        }
    }

    // butterfly-reduce within each 16-lane row group
#pragma unroll
    for (int off = 1; off < 16; off <<= 1) {
        sum0 += __shfl_xor(sum0, off);
        sum1 += __shfl_xor(sum1, off);
        sum2 += __shfl_xor(sum2, off);
#pragma unroll
        for (int k = 0; k < KE; ++k) {
            acc0[k] += __shfl_xor(acc0[k], off);
            acc1[k] += __shfl_xor(acc1[k], off);
            acc2[k] += __shfl_xor(acc2[k], off);
        }
    }
    if (l == 0) {
        float* p0 = part + ((((size_t)ms * NATTR + 0) * H + h) * N + n) * 8;
        float* p1 = part + ((((size_t)ms * NATTR + 1) * H + h) * N + n) * 8;
        float* p2 = part + ((((size_t)ms * NATTR + 2) * H + h) * N + n) * 8;
#pragma unroll
        for (int k = 0; k < KE; ++k) { p0[k] = acc0[k]; p1[k] = acc1[k]; p2[k] = acc2[k]; }
        p0[7] = sum0; p1[7] = sum1; p2[7] = sum2;
    }
}

// ---------------------------------------------------------------------------
// feat2 = [feat | nf_e] @ Wct + bct; s2 = feat2·an_s; n2 = feat2·an_n
// nf_e assembled from edge-attn partials: (Σ acc)/(Σ sum) + be.
template <int K, int KE>
__global__ void k_feat2(const float* __restrict__ feat,   // [3][8][N][16]
                        const float* __restrict__ part,   // [MS][3][8][N][8]
                        const float* __restrict__ be,     // [8][KE]
                        const float* __restrict__ Wct,    // [8][K+KE][K]
                        const float* __restrict__ bct,    // [8][K]
                        const float* __restrict__ ans,    // [3][8][K]
                        const float* __restrict__ ann,    // [3][8][K]
                        float* __restrict__ feat2,        // [3][8][N][16]
                        float* __restrict__ s2,           // [3][8][N]
                        float* __restrict__ n2) {         // [3][8][N]
    constexpr int CIN = K + KE;
    int a = blockIdx.x / H, h = blockIdx.x % H;
    __shared__ float sW[CIN * K];
    __shared__ float sIn[N * CIN];
    __shared__ float sOut[N * K];
    for (int i = threadIdx.x; i < CIN * K; i += 256) sW[i] = Wct[h * CIN * K + i];
    for (int i = threadIdx.x; i < N * K; i += 256) {
        int n = i / K, k = i % K;
        sIn[n * CIN + k] = feat[((a * H + h) * N + n) * 16 + k];
    }
    for (int i = threadIdx.x; i < N * KE; i += 256) {
        int n = i / KE, k = i % KE;
        float av = 0.f, sv = 0.f;
        for (int ms = 0; ms < MS; ++ms) {
            const float* pp = part + ((((size_t)ms * NATTR + a) * H + h) * N + n) * 8;
            av += pp[k];
            sv += pp[7];
        }
        sIn[n * CIN + K + k] = av / sv + be[h * KE + k];
    }
    __syncthreads();
    for (int o = threadIdx.x; o < N * K; o += 256) {
        int n = o / K, k = o % K;
        float acc = bct[h * K + k];
        for (int c = 0; c < CIN; ++c) acc += sIn[n * CIN + c] * sW[c * K + k];
        sOut[o] = acc;
        feat2[((a * H + h) * N + n) * 16 + k] = acc;
    }
    __syncthreads();
    for (int n = threadIdx.x; n < N; n += 256) {
        float ss = 0.f, nn = 0.f;
        for (int k = 0; k < K; ++k) {
            ss += sOut[n * K + k] * ans[(a * H + h) * K + k];
            nn += sOut[n * K + k] * ann[(a * H + h) * K + k];
        }
        s2[(a * H + h) * N + n] = ss;
        n2[(a * H + h) * N + n] = nn;
    }
}

// ---------------------------------------------------------------------------
// c[a][m] = colsum(E_info); d[a][h][m] = n2[a][h]·E_info[:,m]
__global__ void k_cd(const float* __restrict__ Einfo,  // [3][N][N]
                     const float* __restrict__ n2,     // [3][8][N]
                     float* __restrict__ cE,           // [3][N]
                     float* __restrict__ dE) {         // [3][8][N]
    int a = blockIdx.x;
    int m = threadIdx.x;  // 128 threads
    __shared__ float sn2[H * N];
    for (int i = threadIdx.x; i < H * N; i += 128) sn2[i] = n2[a * H * N + i];
    __syncthreads();
    const float* Ep = Einfo + (size_t)a * N * N;
    float c = 0.f, dacc[H];
#pragma unroll
    for (int h = 0; h < H; ++h) dacc[h] = 0.f;
    for (int j = 0; j < N; ++j) {
        float v = Ep[j * N + m];
        c += v;
#pragma unroll
        for (int h = 0; h < H; ++h) dacc[h] += sn2[h * N + j] * v;
    }
    cE[a * N + m] = c;
#pragma unroll
    for (int h = 0; h < H; ++h) dE[(a * H + h) * N + m] = dacc[h];
}

// ---------------------------------------------------------------------------
// Node attention + elu + output write. One block per (a,h,i), 128 threads.
template <int K>
__global__ void __launch_bounds__(128)
k_node_attn(const float* __restrict__ feat2,   // [3][8][N][16]
            const float* __restrict__ s2,      // [3][8][N]
            const float* __restrict__ cE,      // [3][N]
            const float* __restrict__ dE,      // [3][8][N]
            const float* __restrict__ Amat,    // [3][N][N]
            const float* __restrict__ bn,      // [3][8][K]
            float* __restrict__ out, int outOff,
            float* __restrict__ Xh,            // [3][N][128] or nullptr
            float* __restrict__ EinfoNext) {   // [3][N][N] or nullptr
    int b = blockIdx.x;
    int i = b & (N - 1);
    int h = (b >> 7) & (H - 1);
    int a = b >> 10;
    int m = threadIdx.x;

    float s = s2[(a * H + h) * N + i];
    float v = leaky(s * cE[a * N + m] + dE[(a * H + h) * N + m]) +
              Amat[(a * N + i) * N + m];

    __shared__ float red[N];
    __shared__ float salpha[N];
    red[m] = v; __syncthreads();
    for (int st = 64; st > 0; st >>= 1) {
        if (m < st) red[m] = fmaxf(red[m], red[m + st]);
        __syncthreads();
    }
    float gmx = red[0]; __syncthreads();
    float p = __expf(v - gmx);
    red[m] = p; __syncthreads();
    for (int st = 64; st > 0; st >>= 1) {
        if (m < st) red[m] += red[m + st];
        __syncthreads();
    }
    float gsum = red[0]; __syncthreads();
    float alpha = p / gsum;
    salpha[m] = alpha;
    if (EinfoNext != nullptr && h == H - 1)
        EinfoNext[(a * N + i) * N + m] = alpha;
    __syncthreads();

    if (m < K) {
        float acc = bn[(a * H + h) * K + m];
        for (int mm = 0; mm < N; ++mm)
            acc += salpha[mm] * feat2[((a * H + h) * N + mm) * 16 + m];
        float e = acc > 0.f ? acc : __expf(acc) - 1.f;  // elu
        out[(i * NATTR + a) * OUTW + outOff + h * K + m] = e;
        if (Xh != nullptr) Xh[(a * N + i) * F + h * K + m] = e;
    }
}

// ---------------------------------------------------------------------------
extern "C" void kernel_launch(void* const* d_in, const int* in_sizes, int n_in,
                              void* d_out, int out_size, void* d_ws, size_t ws_size,
                              hipStream_t stream) {
    const float* X    = (const float*)d_in[0];
    const float* A    = (const float*)d_in[1];
    const float* E    = (const float*)d_in[2];
    const float* adj  = (const float*)d_in[3];
    const float* Wn0  = (const float*)d_in[4];
    const float* bn0  = (const float*)d_in[5];
    const float* an0s = (const float*)d_in[6];
    const float* an0n = (const float*)d_in[7];
    const float* Wn1  = (const float*)d_in[8];
    const float* bn1  = (const float*)d_in[9];
    const float* an1s = (const float*)d_in[10];
    const float* an1n = (const float*)d_in[11];
    const float* We0  = (const float*)d_in[12];
    const float* be0  = (const float*)d_in[13];
    const float* We1  = (const float*)d_in[14];
    const float* be1  = (const float*)d_in[15];
    const float* Wct0 = (const float*)d_in[16];
    const float* bct0 = (const float*)d_in[17];
    const float* Wct1 = (const float*)d_in[18];
    const float* bct1 = (const float*)d_in[19];
    const float* ae0s = (const float*)d_in[20];
    const float* ae0n = (const float*)d_in[21];
    const float* ae1s = (const float*)d_in[22];
    const float* ae1n = (const float*)d_in[23];
    float* out = (float*)d_out;

    float* p = (float*)d_ws;
    float* feat  = p; p += NATTR * H * N * 16;
    float* aself = p; p += NATTR * H * N;
    float* fe0   = p; p += H * M * 4;
    float* ae0e  = p; p += H * M;
    float* fe1   = p; p += H * M * 2;
    float* ae1e  = p; p += H * M;
    float* part  = p; p += (size_t)MS * NATTR * H * N * 8;
    float* feat2 = p; p += NATTR * H * N * 16;
    float* s2b   = p; p += NATTR * H * N;
    float* n2b   = p; p += NATTR * H * N;
    float* cb    = p; p += NATTR * N;
    float* db    = p; p += NATTR * H * N;
    float* einfo = p; p += NATTR * N * N;
    float* xh    = p; p += NATTR * N * F;

    k_copy_x<<<dim3(192), dim3(256), 0, stream>>>(X, out);
    k_feat_e<<<dim3(64), dim3(256), 0, stream>>>(E, We0, ae0n, We1, ae1n,
                                                 fe0, ae0e, fe1, ae1e);

    // ---- layer 0 ----
    k_feat<16><<<dim3(24), dim3(256), 0, stream>>>(X, 0, Wn0, ae0s, feat, aself);
    k_edge_attn<4><<<dim3(H * 8 * MS), dim3(256), 0, stream>>>(fe0, ae0e, aself, adj, part);
    k_feat2<16, 4><<<dim3(24), dim3(256), 0, stream>>>(feat, part, be0, Wct0, bct0,
                                                       an0s, an0n, feat2, s2b, n2b);
    k_cd<<<dim3(3), dim3(128), 0, stream>>>(E, n2b, cb, db);
    k_node_attn<16><<<dim3(3072), dim3(128), 0, stream>>>(feat2, s2b, cb, db, A, bn0,
                                                          out, F, xh, einfo);

    // ---- layer 1 ----
    k_feat<8><<<dim3(24), dim3(256), 0, stream>>>(xh, N * F, Wn1, ae1s, feat, aself);
    k_edge_attn<2><<<dim3(H * 8 * MS), dim3(256), 0, stream>>>(fe1, ae1e, aself, adj, part);
    k_feat2<8, 2><<<dim3(24), dim3(256), 0, stream>>>(feat, part, be1, Wct1, bct1,
                                                      an1s, an1n, feat2, s2b, n2b);
    k_cd<<<dim3(3), dim3(128), 0, stream>>>(einfo, n2b, cb, db);
    k_node_attn<8><<<dim3(3072), dim3(128), 0, stream>>>(feat2, s2b, cb, db, A, bn1,
                                                         out, F + 128, nullptr, nullptr);
}

// Round 3
// 121.263 us; speedup vs baseline: 2.0902x; 1.1830x over previous
//
#include <hip/hip_runtime.h>

static constexpr int N = 128;
static constexpr int F = 128;
static constexpr int H = 8;
static constexpr int NATTR = 3;
static constexpr int M = N * N;        // 16384
static constexpr int OUTW = 320;       // F + 8*16 + 8*8
static constexpr int MSL = 32;         // m-splits in edge attention
static constexpr int HG = 2;           // heads per edge-attn block

__device__ __forceinline__ float leaky(float x) { return x >= 0.f ? x : 0.2f * x; }

// ---------------------------------------------------------------------------
// Front kernel: blocks [0,64) edge features both layers; [64,256) copy X to
// out; [256,280) layer-0 node features. All independent.
__global__ void __launch_bounds__(256)
k_front(const float* __restrict__ X, const float* __restrict__ E,
        const float* __restrict__ We0, const float* __restrict__ ae0n,
        const float* __restrict__ We1, const float* __restrict__ ae1n,
        const float* __restrict__ Wn0, const float* __restrict__ ae0s,
        float* __restrict__ out,
        float* __restrict__ fe0, float* __restrict__ ae0,
        float* __restrict__ fe1, float* __restrict__ ae1,
        float* __restrict__ feat, float* __restrict__ a_self) {
    __shared__ float smem[4096];
    int b = blockIdx.x;
    if (b < 64) {
        // ---- edge features, both layers (fe1 = E @ (We0_flat @ We1)) ----
        float* sW0 = smem;            // 96
        float* sA0 = smem + 96;       // 32
        float* sA1 = smem + 128;      // 16
        float* sWc = smem + 144;      // 48
        if (threadIdx.x < 96) sW0[threadIdx.x] = We0[threadIdx.x];
        if (threadIdx.x < 32) sA0[threadIdx.x] = ae0n[threadIdx.x];
        if (threadIdx.x < 16) sA1[threadIdx.x] = ae1n[threadIdx.x];
        __syncthreads();
        if (threadIdx.x < 48) {
            int h2 = threadIdx.x / 6;
            int rem = threadIdx.x % 6;
            int at = rem >> 1, k2 = rem & 1;
            float acc = 0.f;
            for (int c = 0; c < 32; ++c)
                acc += sW0[((c >> 2) * 3 + at) * 4 + (c & 3)] * We1[(h2 * 32 + c) * 2 + k2];
            sWc[(h2 * 3 + at) * 2 + k2] = acc;
        }
        __syncthreads();
        int m = b * 256 + threadIdx.x;
        float e0 = E[m], e1 = E[M + m], e2 = E[2 * M + m];
        for (int h = 0; h < H; ++h) {
            float4 v;
            float* vp = &v.x;
            float aa = 0.f;
#pragma unroll
            for (int ke = 0; ke < 4; ++ke) {
                float f = e0 * sW0[(h * 3 + 0) * 4 + ke] +
                          e1 * sW0[(h * 3 + 1) * 4 + ke] +
                          e2 * sW0[(h * 3 + 2) * 4 + ke];
                vp[ke] = f;
                aa += f * sA0[h * 4 + ke];
            }
            *(float4*)&fe0[(size_t)(h * M + m) * 4] = v;
            ae0[h * M + m] = aa;
            float f0 = e0 * sWc[(h * 3 + 0) * 2 + 0] + e1 * sWc[(h * 3 + 1) * 2 + 0] +
                       e2 * sWc[(h * 3 + 2) * 2 + 0];
            float f1 = e0 * sWc[(h * 3 + 0) * 2 + 1] + e1 * sWc[(h * 3 + 1) * 2 + 1] +
                       e2 * sWc[(h * 3 + 2) * 2 + 1];
            *(float2*)&fe1[(size_t)(h * M + m) * 2] = make_float2(f0, f1);
            ae1[h * M + m] = f0 * sA1[h * 2 + 0] + f1 * sA1[h * 2 + 1];
        }
    } else if (b < 256) {
        // ---- out[:, a, 0:128] = X ----
        int idx = (b - 64) * 256 + threadIdx.x;
        int f = idx % F;
        int rest = idx / F;
        int a = rest % NATTR;
        int n = rest / NATTR;
        out[(n * NATTR + a) * OUTW + f] = X[n * F + f];
    } else {
        // ---- layer-0 node features (K=16) ----
        constexpr int K = 16;
        int ab = b - 256;
        int a = ab / H, h = ab % H;
        const float* Wp = Wn0 + (size_t)(a * H + h) * F * K;
        float* sW = smem;            // F*K = 2048
        float* sF = smem + F * K;    // N*K = 2048
        for (int i = threadIdx.x; i < F * K; i += 256) sW[i] = Wp[i];
        __syncthreads();
        for (int o = threadIdx.x; o < N * K; o += 256) {
            int n = o / K, k = o % K;
            const float* xr = X + n * F;
            float acc = 0.f;
            for (int f = 0; f < F; ++f) acc += xr[f] * sW[f * K + k];
            sF[o] = acc;
            feat[((a * H + h) * N + n) * 16 + k] = acc;
        }
        __syncthreads();
        for (int n = threadIdx.x; n < N; n += 256) {
            float acc = 0.f;
            for (int k = 0; k < K; ++k) acc += sF[n * K + k] * ae0s[h * K + k];
            a_self[(a * H + h) * N + n] = acc;
        }
    }
}

// ---------------------------------------------------------------------------
// Node features (layer 1 standalone)
template <int K>
__global__ void k_feat(const float* __restrict__ Xsrc, int aStride,
                       const float* __restrict__ Wn,    // [3][8][F][K]
                       const float* __restrict__ aes,   // [8][K]
                       float* __restrict__ feat,        // [3][8][N][16]
                       float* __restrict__ a_self) {    // [3][8][N]
    int a = blockIdx.x / H, h = blockIdx.x % H;
    const float* Xp = Xsrc + (size_t)a * aStride;
    const float* Wp = Wn + (size_t)(a * H + h) * F * K;
    __shared__ float sW[F * 16];
    __shared__ float sF[N * 16];
    for (int i = threadIdx.x; i < F * K; i += 256) sW[i] = Wp[i];
    __syncthreads();
    for (int o = threadIdx.x; o < N * K; o += 256) {
        int n = o / K, k = o % K;
        const float* xr = Xp + n * F;
        float acc = 0.f;
        for (int f = 0; f < F; ++f) acc += xr[f] * sW[f * K + k];
        sF[o] = acc;
        feat[((a * H + h) * N + n) * 16 + k] = acc;
    }
    __syncthreads();
    for (int n = threadIdx.x; n < N; n += 256) {
        float acc = 0.f;
        for (int k = 0; k < K; ++k) acc += sF[n * K + k] * aes[h * K + k];
        a_self[(a * H + h) * N + n] = acc;
    }
}

// ---------------------------------------------------------------------------
// Edge-to-node attention. Block = (head-pair, n-tile of 16, m-chunk of 512).
// Covers all 3 attrs and HG=2 heads; adj read amortized over heads+attrs.
// No online max (logits O(1); f32 exp exact enough). Partials to `part`.
template <int KE>
__global__ void __launch_bounds__(256)
k_edge_attn(const float* __restrict__ fe,      // [8][M][KE]
            const float* __restrict__ ae,      // [8][M]
            const float* __restrict__ a_self,  // [3][8][N]
            const float* __restrict__ adj,     // [N][M]
            float* __restrict__ part) {        // [3][8][N][MSL][8]
    constexpr int CH = M / MSL;                // 512
    int b = blockIdx.x;                        // hq*256 + nt*32 + ms
    int ms = b & (MSL - 1);
    int nt = (b >> 5) & 7;
    int h0 = (b >> 8) * HG;
    int tid = threadIdx.x;
    int r = tid >> 4, l = tid & 15;
    int n = nt * 16 + r;
    int m0 = ms * CH;

    float as[NATTR][HG];
#pragma unroll
    for (int a = 0; a < NATTR; ++a)
#pragma unroll
        for (int hh = 0; hh < HG; ++hh)
            as[a][hh] = a_self[(a * H + h0 + hh) * N + n];

    const float* adjp = adj + (size_t)n * M + m0;
    const float* aep[HG];
    const float* fep[HG];
#pragma unroll
    for (int hh = 0; hh < HG; ++hh) {
        aep[hh] = ae + (size_t)(h0 + hh) * M + m0;
        fep[hh] = fe + ((size_t)(h0 + hh) * M + m0) * KE;
    }

    float sum[HG][NATTR];
    float acc[HG][NATTR][KE];
#pragma unroll
    for (int hh = 0; hh < HG; ++hh)
#pragma unroll
        for (int a = 0; a < NATTR; ++a) {
            sum[hh][a] = 0.f;
#pragma unroll
            for (int k = 0; k < KE; ++k) acc[hh][a][k] = 0.f;
        }

    for (int i = l * 4; i < CH; i += 64) {
        const float4 av = *(const float4*)(adjp + i);
        float4 ev[HG];
        float fv[HG][4][KE];
#pragma unroll
        for (int hh = 0; hh < HG; ++hh) {
            ev[hh] = *(const float4*)(aep[hh] + i);
#pragma unroll
            for (int j = 0; j < 4; ++j) {
                if (KE == 4) {
                    const float4 fq = *(const float4*)(fep[hh] + (i + j) * 4);
                    fv[hh][j][0] = fq.x; fv[hh][j][1] = fq.y;
                    fv[hh][j][2] = fq.z; fv[hh][j][3] = fq.w;
                } else {
                    const float2 fq = *(const float2*)(fep[hh] + (i + j) * 2);
                    fv[hh][j][0] = fq.x; fv[hh][j][1] = fq.y;
                }
            }
        }
#pragma unroll
        for (int j = 0; j < 4; ++j) {
            float adjv = reinterpret_cast<const float*>(&av)[j];
#pragma unroll
            for (int hh = 0; hh < HG; ++hh) {
                float aev = reinterpret_cast<const float*>(&ev[hh])[j];
#pragma unroll
                for (int a = 0; a < NATTR; ++a) {
                    float t = as[a][hh] + aev;
                    float p = __expf((t >= 0.f ? t : 0.2f * t) + adjv);
                    sum[hh][a] += p;
#pragma unroll
                    for (int k = 0; k < KE; ++k) acc[hh][a][k] += p * fv[hh][j][k];
                }
            }
        }
    }

    // butterfly-reduce within each 16-lane row group
#pragma unroll
    for (int off = 1; off < 16; off <<= 1) {
#pragma unroll
        for (int hh = 0; hh < HG; ++hh)
#pragma unroll
            for (int a = 0; a < NATTR; ++a) {
                sum[hh][a] += __shfl_xor(sum[hh][a], off);
#pragma unroll
                for (int k = 0; k < KE; ++k) acc[hh][a][k] += __shfl_xor(acc[hh][a][k], off);
            }
    }
    if (l == 0) {
#pragma unroll
        for (int hh = 0; hh < HG; ++hh)
#pragma unroll
            for (int a = 0; a < NATTR; ++a) {
                float* pp = part + (((size_t)(a * H + h0 + hh) * N + n) * MSL + ms) * 8;
#pragma unroll
                for (int k = 0; k < KE; ++k) pp[k] = acc[hh][a][k];
                pp[7] = sum[hh][a];
            }
    }
}

// ---------------------------------------------------------------------------
// Mid kernel per (a,h): assemble nf_e from partials, feat2 = [feat|nf_e]@Wct
// + bct, s2/n2, then dE[m] = n2·Einfo[:,m] (and cE = colsum for h==0).
template <int K, int KE>
__global__ void __launch_bounds__(256)
k_mid(const float* __restrict__ feat,   // [3][8][N][16]
      const float* __restrict__ part,   // [3][8][N][MSL][8]
      const float* __restrict__ be,     // [8][KE]
      const float* __restrict__ Wct,    // [8][K+KE][K]
      const float* __restrict__ bct,    // [8][K]
      const float* __restrict__ ans,    // [3][8][K]
      const float* __restrict__ ann,    // [3][8][K]
      const float* __restrict__ Einfo,  // [3][N][N]
      float* __restrict__ feat2,        // [3][8][N][16]
      float* __restrict__ s2,           // [3][8][N]
      float* __restrict__ dE,           // [3][8][N]
      float* __restrict__ cE) {         // [3][N]
    constexpr int CIN = K + KE;
    int a = blockIdx.x / H, h = blockIdx.x % H;
    __shared__ float sW[CIN * K];
    __shared__ float sIn[N * CIN];
    __shared__ float sOut[N * K];
    __shared__ float sn2[N];
    for (int i = threadIdx.x; i < CIN * K; i += 256) sW[i] = Wct[h * CIN * K + i];
    for (int i = threadIdx.x; i < N * K; i += 256) {
        int n = i / K, k = i % K;
        sIn[n * CIN + k] = feat[((a * H + h) * N + n) * 16 + k];
    }
    if (threadIdx.x < N) {
        int n = threadIdx.x;
        float4 av = make_float4(0.f, 0.f, 0.f, 0.f);
        float sv = 0.f;
        const float* pp = part + ((size_t)(a * H + h) * N + n) * MSL * 8;
        for (int ms = 0; ms < MSL; ++ms) {
            const float4 x = *(const float4*)(pp + ms * 8);
            const float4 y = *(const float4*)(pp + ms * 8 + 4);
            av.x += x.x; av.y += x.y;
            if (KE == 4) { av.z += x.z; av.w += x.w; }
            sv += y.w;
        }
        float inv = 1.f / sv;
        sIn[n * CIN + K + 0] = av.x * inv + be[h * KE + 0];
        sIn[n * CIN + K + 1] = av.y * inv + be[h * KE + 1];
        if (KE == 4) {
            sIn[n * CIN + K + 2] = av.z * inv + be[h * KE + 2];
            sIn[n * CIN + K + 3] = av.w * inv + be[h * KE + 3];
        }
    }
    __syncthreads();
    for (int o = threadIdx.x; o < N * K; o += 256) {
        int n = o / K, k = o % K;
        float acc = bct[h * K + k];
        for (int c = 0; c < CIN; ++c) acc += sIn[n * CIN + c] * sW[c * K + k];
        sOut[o] = acc;
        feat2[((a * H + h) * N + n) * 16 + k] = acc;
    }
    __syncthreads();
    if (threadIdx.x < N) {
        int n = threadIdx.x;
        float ss = 0.f, nn = 0.f;
        for (int k = 0; k < K; ++k) {
            ss += sOut[n * K + k] * ans[(a * H + h) * K + k];
            nn += sOut[n * K + k] * ann[(a * H + h) * K + k];
        }
        s2[(a * H + h) * N + n] = ss;
        sn2[n] = nn;
    }
    __syncthreads();
    if (threadIdx.x < N) {
        int m = threadIdx.x;
        const float* Ep = Einfo + (size_t)a * N * N;
        float dacc = 0.f, cacc = 0.f;
        for (int j = 0; j < N; ++j) {
            float v = Ep[j * N + m];
            dacc += sn2[j] * v;
            cacc += v;
        }
        dE[(a * H + h) * N + m] = dacc;
        if (h == 0) cE[a * N + m] = cacc;
    }
}

// ---------------------------------------------------------------------------
// Node attention + elu + output write. One block per (a,h,i), 128 threads.
template <int K>
__global__ void __launch_bounds__(128)
k_node_attn(const float* __restrict__ feat2,   // [3][8][N][16]
            const float* __restrict__ s2,      // [3][8][N]
            const float* __restrict__ cE,      // [3][N]
            const float* __restrict__ dE,      // [3][8][N]
            const float* __restrict__ Amat,    // [3][N][N]
            const float* __restrict__ bn,      // [3][8][K]
            float* __restrict__ out, int outOff,
            float* __restrict__ Xh,            // [3][N][128] or nullptr
            float* __restrict__ EinfoNext) {   // [3][N][N] or nullptr
    int b = blockIdx.x;
    int i = b & (N - 1);
    int h = (b >> 7) & (H - 1);
    int a = b >> 10;
    int m = threadIdx.x;

    float s = s2[(a * H + h) * N + i];
    float v = leaky(s * cE[a * N + m] + dE[(a * H + h) * N + m]) +
              Amat[(a * N + i) * N + m];

    __shared__ float red[N];
    __shared__ float salpha[N];
    red[m] = v; __syncthreads();
    for (int st = 64; st > 0; st >>= 1) {
        if (m < st) red[m] = fmaxf(red[m], red[m + st]);
        __syncthreads();
    }
    float gmx = red[0]; __syncthreads();
    float p = __expf(v - gmx);
    red[m] = p; __syncthreads();
    for (int st = 64; st > 0; st >>= 1) {
        if (m < st) red[m] += red[m + st];
        __syncthreads();
    }
    float gsum = red[0]; __syncthreads();
    float alpha = p / gsum;
    salpha[m] = alpha;
    if (EinfoNext != nullptr && h == H - 1)
        EinfoNext[(a * N + i) * N + m] = alpha;
    __syncthreads();

    // phase 2: 8 groups x 16 lanes; group g covers mm in [g*16, g*16+16)
    int g = m >> 4, k = m & 15;
    float acc = 0.f;
    if (k < K) {
        const float* f2 = feat2 + ((size_t)(a * H + h) * N + g * 16) * 16 + k;
        for (int mm = 0; mm < 16; ++mm)
            acc += salpha[g * 16 + mm] * f2[mm * 16];
    }
    red[m] = acc; __syncthreads();
    if (m < K) {
        float total = bn[(a * H + h) * K + m];
#pragma unroll
        for (int gg = 0; gg < 8; ++gg) total += red[gg * 16 + m];
        float e = total > 0.f ? total : __expf(total) - 1.f;  // elu
        out[(i * NATTR + a) * OUTW + outOff + h * K + m] = e;
        if (Xh != nullptr) Xh[(a * N + i) * F + h * K + m] = e;
    }
}

// ---------------------------------------------------------------------------
extern "C" void kernel_launch(void* const* d_in, const int* in_sizes, int n_in,
                              void* d_out, int out_size, void* d_ws, size_t ws_size,
                              hipStream_t stream) {
    const float* X    = (const float*)d_in[0];
    const float* A    = (const float*)d_in[1];
    const float* E    = (const float*)d_in[2];
    const float* adj  = (const float*)d_in[3];
    const float* Wn0  = (const float*)d_in[4];
    const float* bn0  = (const float*)d_in[5];
    const float* an0s = (const float*)d_in[6];
    const float* an0n = (const float*)d_in[7];
    const float* Wn1  = (const float*)d_in[8];
    const float* bn1  = (const float*)d_in[9];
    const float* an1s = (const float*)d_in[10];
    const float* an1n = (const float*)d_in[11];
    const float* We0  = (const float*)d_in[12];
    const float* be0  = (const float*)d_in[13];
    const float* We1  = (const float*)d_in[14];
    const float* be1  = (const float*)d_in[15];
    const float* Wct0 = (const float*)d_in[16];
    const float* bct0 = (const float*)d_in[17];
    const float* Wct1 = (const float*)d_in[18];
    const float* bct1 = (const float*)d_in[19];
    const float* ae0s = (const float*)d_in[20];
    const float* ae0n = (const float*)d_in[21];
    const float* ae1s = (const float*)d_in[22];
    const float* ae1n = (const float*)d_in[23];
    float* out = (float*)d_out;

    float* p = (float*)d_ws;
    float* feat  = p; p += NATTR * H * N * 16;
    float* aself = p; p += NATTR * H * N;
    float* fe0   = p; p += H * M * 4;
    float* ae0e  = p; p += H * M;
    float* fe1   = p; p += H * M * 2;
    float* ae1e  = p; p += H * M;
    float* part  = p; p += (size_t)NATTR * H * N * MSL * 8;
    float* feat2 = p; p += NATTR * H * N * 16;
    float* s2b   = p; p += NATTR * H * N;
    float* cb    = p; p += NATTR * N;
    float* db    = p; p += NATTR * H * N;
    float* einfo = p; p += NATTR * N * N;
    float* xh    = p; p += NATTR * N * F;

    k_front<<<dim3(280), dim3(256), 0, stream>>>(X, E, We0, ae0n, We1, ae1n,
                                                 Wn0, ae0s, out, fe0, ae0e,
                                                 fe1, ae1e, feat, aself);

    // ---- layer 0 ----
    k_edge_attn<4><<<dim3((H / HG) * 8 * MSL), dim3(256), 0, stream>>>(
        fe0, ae0e, aself, adj, part);
    k_mid<16, 4><<<dim3(24), dim3(256), 0, stream>>>(feat, part, be0, Wct0, bct0,
                                                     an0s, an0n, E, feat2, s2b, db, cb);
    k_node_attn<16><<<dim3(3072), dim3(128), 0, stream>>>(feat2, s2b, cb, db, A, bn0,
                                                          out, F, xh, einfo);

    // ---- layer 1 ----
    k_feat<8><<<dim3(24), dim3(256), 0, stream>>>(xh, N * F, Wn1, ae1s, feat, aself);
    k_edge_attn<2><<<dim3((H / HG) * 8 * MSL), dim3(256), 0, stream>>>(
        fe1, ae1e, aself, adj, part);
    k_mid<8, 2><<<dim3(24), dim3(256), 0, stream>>>(feat, part, be1, Wct1, bct1,
                                                    an1s, an1n, einfo, feat2, s2b, db, cb);
    k_node_attn<8><<<dim3(3072), dim3(128), 0, stream>>>(feat2, s2b, cb, db, A, bn1,
                                                         out, F + 128, nullptr, nullptr);
}

// Round 4
// 111.684 us; speedup vs baseline: 2.2695x; 1.0858x over previous
//
#include <hip/hip_runtime.h>

static constexpr int N = 128;
static constexpr int F = 128;
static constexpr int H = 8;
static constexpr int NATTR = 3;
static constexpr int M = N * N;        // 16384
static constexpr int OUTW = 320;       // F + 8*16 + 8*8
static constexpr int MSL = 32;         // m-splits in edge attention
static constexpr int HG = 2;           // heads per edge-attn block
static constexpr float LOG2E = 1.4426950408889634f;

__device__ __forceinline__ float leaky(float x) { return fmaxf(x, 0.2f * x); }

// ---------------------------------------------------------------------------
// Front kernel: b<64 edge features (both layers, log2e-scaled ae);
// b in [64,256) copy X to out; [256,280) layer-0 node feats (+scaled aself);
// b==280 wvec = log2e * (Wn1 @ ae1s) for inline aself in edge-attn L1.
__global__ void __launch_bounds__(256)
k_front(const float* __restrict__ X, const float* __restrict__ E,
        const float* __restrict__ We0, const float* __restrict__ ae0n,
        const float* __restrict__ We1, const float* __restrict__ ae1n,
        const float* __restrict__ Wn0, const float* __restrict__ ae0s,
        const float* __restrict__ Wn1, const float* __restrict__ ae1s,
        float* __restrict__ out,
        float* __restrict__ fe0, float* __restrict__ ae0,
        float* __restrict__ fe1, float* __restrict__ ae1,
        float* __restrict__ feat, float* __restrict__ a_self,
        float* __restrict__ wvec) {
    __shared__ float smem[4096];
    int b = blockIdx.x;
    if (b < 64) {
        float* sW0 = smem;            // 96
        float* sA0 = smem + 96;       // 32
        float* sA1 = smem + 128;      // 16
        float* sWc = smem + 144;      // 48
        if (threadIdx.x < 96) sW0[threadIdx.x] = We0[threadIdx.x];
        if (threadIdx.x < 32) sA0[threadIdx.x] = ae0n[threadIdx.x];
        if (threadIdx.x < 16) sA1[threadIdx.x] = ae1n[threadIdx.x];
        __syncthreads();
        if (threadIdx.x < 48) {
            int h2 = threadIdx.x / 6;
            int rem = threadIdx.x % 6;
            int at = rem >> 1, k2 = rem & 1;
            float acc = 0.f;
            for (int c = 0; c < 32; ++c)
                acc += sW0[((c >> 2) * 3 + at) * 4 + (c & 3)] * We1[(h2 * 32 + c) * 2 + k2];
            sWc[(h2 * 3 + at) * 2 + k2] = acc;
        }
        __syncthreads();
        int m = b * 256 + threadIdx.x;
        float e0 = E[m], e1 = E[M + m], e2 = E[2 * M + m];
        for (int h = 0; h < H; ++h) {
            float4 v;
            float* vp = &v.x;
            float aa = 0.f;
#pragma unroll
            for (int ke = 0; ke < 4; ++ke) {
                float f = e0 * sW0[(h * 3 + 0) * 4 + ke] +
                          e1 * sW0[(h * 3 + 1) * 4 + ke] +
                          e2 * sW0[(h * 3 + 2) * 4 + ke];
                vp[ke] = f;
                aa += f * sA0[h * 4 + ke];
            }
            *(float4*)&fe0[(size_t)(h * M + m) * 4] = v;
            ae0[h * M + m] = aa * LOG2E;
            float f0 = e0 * sWc[(h * 3 + 0) * 2 + 0] + e1 * sWc[(h * 3 + 1) * 2 + 0] +
                       e2 * sWc[(h * 3 + 2) * 2 + 0];
            float f1 = e0 * sWc[(h * 3 + 0) * 2 + 1] + e1 * sWc[(h * 3 + 1) * 2 + 1] +
                       e2 * sWc[(h * 3 + 2) * 2 + 1];
            *(float2*)&fe1[(size_t)(h * M + m) * 2] = make_float2(f0, f1);
            ae1[h * M + m] = (f0 * sA1[h * 2 + 0] + f1 * sA1[h * 2 + 1]) * LOG2E;
        }
    } else if (b < 256) {
        int idx = (b - 64) * 256 + threadIdx.x;
        int f = idx % F;
        int rest = idx / F;
        int a = rest % NATTR;
        int n = rest / NATTR;
        out[(n * NATTR + a) * OUTW + f] = X[n * F + f];
    } else if (b < 280) {
        // ---- layer-0 node features (K=16), aself scaled by log2e ----
        constexpr int K = 16;
        int ab = b - 256;
        int a = ab / H, h = ab % H;
        const float* Wp = Wn0 + (size_t)(a * H + h) * F * K;
        float* sW = smem;
        float* sF = smem + F * K;
        for (int i = threadIdx.x; i < F * K; i += 256) sW[i] = Wp[i];
        __syncthreads();
        for (int o = threadIdx.x; o < N * K; o += 256) {
            int n = o / K, k = o % K;
            const float* xr = X + n * F;
            float acc = 0.f;
            for (int f = 0; f < F; ++f) acc += xr[f] * sW[f * K + k];
            sF[o] = acc;
            feat[((a * H + h) * N + n) * 16 + k] = acc;
        }
        __syncthreads();
        for (int n = threadIdx.x; n < N; n += 256) {
            float acc = 0.f;
            for (int k = 0; k < K; ++k) acc += sF[n * K + k] * ae0s[h * K + k];
            a_self[(a * H + h) * N + n] = acc * LOG2E;
        }
    } else {
        // ---- wvec[(a*H+h)*F + f] = log2e * sum_k Wn1[a][h][f][k]*ae1s[h][k]
        for (int o = threadIdx.x; o < NATTR * H * F; o += 256) {
            int f = o & (F - 1);
            int ah = o >> 7;
            int h = ah & 7;
            float acc = 0.f;
#pragma unroll
            for (int k = 0; k < 8; ++k)
                acc += Wn1[((size_t)ah * F + f) * 8 + k] * ae1s[h * 8 + k];
            wvec[o] = acc * LOG2E;
        }
    }
}

// ---------------------------------------------------------------------------
// Edge-to-node attention. Block = (head-pair, n-tile of 16, m-chunk of 512),
// covers all 3 attrs. L1 computes a_self inline from xh·wvec (lane-coop dot).
// exp2-based (all logit terms pre-scaled by log2e). Partials to `part`.
template <int KE, bool L1>
__global__ void __launch_bounds__(256)
k_edge_attn(const float* __restrict__ fe,      // [8][M][KE]
            const float* __restrict__ ae,      // [8][M]  (scaled)
            const float* __restrict__ a_self,  // [3][8][N] (scaled) | L0
            const float* __restrict__ xh,      // [3][N][128]        | L1
            const float* __restrict__ wvec,    // [3][8][128] scaled | L1
            const float* __restrict__ adj,     // [N][M]
            float* __restrict__ part) {        // [3][8][N][MSL][8]
    constexpr int CH = M / MSL;                // 512
    int b = blockIdx.x;
    int ms = b & (MSL - 1);
    int nt = (b >> 5) & 7;
    int h0 = (b >> 8) * HG;
    int tid = threadIdx.x;
    int r = tid >> 4, l = tid & 15;
    int n = nt * 16 + r;
    int m0 = ms * CH;

    float as[NATTR][HG];
    if (!L1) {
#pragma unroll
        for (int a = 0; a < NATTR; ++a)
#pragma unroll
            for (int hh = 0; hh < HG; ++hh)
                as[a][hh] = a_self[(a * H + h0 + hh) * N + n];
    } else {
#pragma unroll
        for (int a = 0; a < NATTR; ++a) {
            const float* xr = xh + (size_t)(a * N + n) * F;
            float xv[8];
#pragma unroll
            for (int j = 0; j < 8; ++j) xv[j] = xr[l + 16 * j];
#pragma unroll
            for (int hh = 0; hh < HG; ++hh) {
                const float* wr = wvec + (size_t)(a * H + h0 + hh) * F;
                float d = 0.f;
#pragma unroll
                for (int j = 0; j < 8; ++j) d += xv[j] * wr[l + 16 * j];
#pragma unroll
                for (int off = 1; off < 16; off <<= 1) d += __shfl_xor(d, off);
                as[a][hh] = d;
            }
        }
    }

    const float* adjp = adj + (size_t)n * M + m0;
    const float* aep[HG];
    const float* fep[HG];
#pragma unroll
    for (int hh = 0; hh < HG; ++hh) {
        aep[hh] = ae + (size_t)(h0 + hh) * M + m0;
        fep[hh] = fe + ((size_t)(h0 + hh) * M + m0) * KE;
    }

    float sum[HG][NATTR];
    float acc[HG][NATTR][KE];
#pragma unroll
    for (int hh = 0; hh < HG; ++hh)
#pragma unroll
        for (int a = 0; a < NATTR; ++a) {
            sum[hh][a] = 0.f;
#pragma unroll
            for (int k = 0; k < KE; ++k) acc[hh][a][k] = 0.f;
        }

    for (int i = l * 4; i < CH; i += 64) {
        const float4 av = *(const float4*)(adjp + i);
        float4 ev[HG];
        float fv[HG][4][KE];
#pragma unroll
        for (int hh = 0; hh < HG; ++hh) {
            ev[hh] = *(const float4*)(aep[hh] + i);
#pragma unroll
            for (int j = 0; j < 4; ++j) {
                if (KE == 4) {
                    const float4 fq = *(const float4*)(fep[hh] + (i + j) * 4);
                    fv[hh][j][0] = fq.x; fv[hh][j][1] = fq.y;
                    fv[hh][j][2] = fq.z; fv[hh][j][3] = fq.w;
                } else {
                    const float2 fq = *(const float2*)(fep[hh] + (i + j) * 2);
                    fv[hh][j][0] = fq.x; fv[hh][j][1] = fq.y;
                }
            }
        }
#pragma unroll
        for (int j = 0; j < 4; ++j) {
            float adjv = reinterpret_cast<const float*>(&av)[j] * LOG2E;
#pragma unroll
            for (int hh = 0; hh < HG; ++hh) {
                float aev = reinterpret_cast<const float*>(&ev[hh])[j];
#pragma unroll
                for (int a = 0; a < NATTR; ++a) {
                    float t = as[a][hh] + aev;
                    float p = __builtin_amdgcn_exp2f(fmaxf(t, 0.2f * t) + adjv);
                    sum[hh][a] += p;
#pragma unroll
                    for (int k = 0; k < KE; ++k) acc[hh][a][k] += p * fv[hh][j][k];
                }
            }
        }
    }

#pragma unroll
    for (int off = 1; off < 16; off <<= 1) {
#pragma unroll
        for (int hh = 0; hh < HG; ++hh)
#pragma unroll
            for (int a = 0; a < NATTR; ++a) {
                sum[hh][a] += __shfl_xor(sum[hh][a], off);
#pragma unroll
                for (int k = 0; k < KE; ++k) acc[hh][a][k] += __shfl_xor(acc[hh][a][k], off);
            }
    }
    if (l == 0) {
#pragma unroll
        for (int hh = 0; hh < HG; ++hh)
#pragma unroll
            for (int a = 0; a < NATTR; ++a) {
                float* pp = part + (((size_t)(a * H + h0 + hh) * N + n) * MSL + ms) * 8;
#pragma unroll
                for (int k = 0; k < KE; ++k) pp[k] = acc[hh][a][k];
                pp[7] = sum[hh][a];
            }
    }
}

// ---------------------------------------------------------------------------
// Tail: per (a, h, itile of 16 rows). Assembles nf_e, computes feat2 (LDS),
// s2/n2, dE/cE, then 16 rows of node attention + elu + output. L1 variant
// computes feat from xh @ Wn1 inline.
template <int K, int KE, bool L1>
__global__ void __launch_bounds__(256)
k_tail(const float* __restrict__ feat,     // [3][8][N][16]     | L0
       const float* __restrict__ xh,       // [3][N][128]       | L1
       const float* __restrict__ Wn1,      // [3][8][128][8]    | L1
       const float* __restrict__ part,     // [3][8][N][MSL][8]
       const float* __restrict__ be,       // [8][KE]
       const float* __restrict__ Wct,      // [8][K+KE][K]
       const float* __restrict__ bct,      // [8][K]
       const float* __restrict__ ans,      // [3][8][K]
       const float* __restrict__ ann,      // [3][8][K]
       const float* __restrict__ Einfo,    // [3][N][N]
       const float* __restrict__ Amat,     // [3][N][N]
       const float* __restrict__ bn,       // [3][8][K]
       float* __restrict__ out, int outOff,
       float* __restrict__ xh_out,         // [3][N][128] or nullptr
       float* __restrict__ einfo_out) {    // [3][N][N] or nullptr
    constexpr int CIN = K + KE;
    int b = blockIdx.x;
    int itile = b & 7, h = (b >> 3) & 7, a = b >> 6;
    int tid = threadIdx.x;

    __shared__ float sW[CIN * K];
    __shared__ float sIn[N * CIN];
    __shared__ float sOut[N * K];
    __shared__ float sS2[N];
    __shared__ float sn2[N];
    __shared__ float sdE[N];
    __shared__ float scE[N];
    __shared__ float sAlpha[4][N];
    __shared__ float sRed[256];
    __shared__ float sWn1[L1 ? F * K : 1];

    // ---- phase 0: weights + sIn assembly ----
    for (int i = tid; i < CIN * K; i += 256) sW[i] = Wct[h * CIN * K + i];
    if (L1)
        for (int i = tid; i < F * K; i += 256)
            sWn1[i] = Wn1[(size_t)(a * H + h) * F * K + i];
    if (tid < N) {
        int n = tid;
        const float* pp = part + ((size_t)(a * H + h) * N + n) * MSL * 8;
        float av[4] = {0.f, 0.f, 0.f, 0.f};
        float sv = 0.f;
        for (int ms = 0; ms < MSL; ++ms) {
            const float4 x = *(const float4*)(pp + ms * 8);
            const float4 y = *(const float4*)(pp + ms * 8 + 4);
            av[0] += x.x; av[1] += x.y;
            if (KE == 4) { av[2] += x.z; av[3] += x.w; }
            sv += y.w;
        }
        float inv = 1.f / sv;
#pragma unroll
        for (int k = 0; k < KE; ++k)
            sIn[n * CIN + K + k] = av[k] * inv + be[h * KE + k];
    }
    if (!L1) {
        for (int i = tid; i < N * K; i += 256) {
            int n = i / K, k = i % K;
            sIn[n * CIN + k] = feat[((a * H + h) * N + n) * 16 + k];
        }
    } else {
        __syncthreads();   // sWn1 ready
        for (int o = tid; o < N * K; o += 256) {
            int n = o / K, k = o % K;
            const float* xr = xh + (size_t)(a * N + n) * F;
            float acc = 0.f;
            for (int f = 0; f < F; ++f) acc += xr[f] * sWn1[f * K + k];
            sIn[n * CIN + k] = acc;
        }
    }
    __syncthreads();

    // ---- phase 1: feat2 = sIn @ Wct + bct ----
    for (int o = tid; o < N * K; o += 256) {
        int n = o / K, k = o % K;
        float acc = bct[h * K + k];
        for (int c = 0; c < CIN; ++c) acc += sIn[n * CIN + c] * sW[c * K + k];
        sOut[o] = acc;
    }
    __syncthreads();
    if (tid < N) {
        int n = tid;
        float ss = 0.f, nn = 0.f;
        for (int k = 0; k < K; ++k) {
            ss += sOut[n * K + k] * ans[(a * H + h) * K + k];
            nn += sOut[n * K + k] * ann[(a * H + h) * K + k];
        }
        sS2[n] = ss;
        sn2[n] = nn;
    }
    __syncthreads();

    // ---- phase 2: dE[m] = n2·Einfo[:,m], cE[m] = colsum(Einfo) ----
    {
        int m = tid & 127, w = tid >> 7;
        const float* Ep = Einfo + (size_t)a * M;
        float dacc = 0.f, cacc = 0.f;
        for (int j = w * 64; j < w * 64 + 64; ++j) {
            float v = Ep[j * N + m];
            dacc += sn2[j] * v;
            cacc += v;
        }
        sRed[tid] = dacc;
        sAlpha[w][m] = cacc;
        __syncthreads();
        if (tid < N) {
            sdE[tid] = sRed[tid] + sRed[128 + tid];
            scE[tid] = sAlpha[0][tid] + sAlpha[1][tid];
        }
    }
    __syncthreads();

    // ---- phase 3: node attention, 4 passes x 4 rows (1 wave per row) ----
    for (int pass = 0; pass < 4; ++pass) {
        int r = tid >> 6;          // wave id = row within pass
        int lane = tid & 63;
        int i = itile * 16 + pass * 4 + r;
        float s = sS2[i];
        const float* Ap = Amat + ((size_t)a * N + i) * N;
        float v0 = leaky(s * scE[lane] + sdE[lane]) + Ap[lane];
        float v1 = leaky(s * scE[lane + 64] + sdE[lane + 64]) + Ap[lane + 64];
        float p0 = __expf(v0), p1 = __expf(v1);
        float ssum = p0 + p1;
#pragma unroll
        for (int off = 1; off < 64; off <<= 1) ssum += __shfl_xor(ssum, off);
        float inv = 1.f / ssum;
        float a0 = p0 * inv, a1 = p1 * inv;
        sAlpha[r][lane] = a0;
        sAlpha[r][lane + 64] = a1;
        if (einfo_out != nullptr && h == H - 1) {
            einfo_out[((size_t)a * N + i) * N + lane] = a0;
            einfo_out[((size_t)a * N + i) * N + lane + 64] = a1;
        }
        __syncthreads();
        // PV: per row, 4 groups x 16 k-lanes; group g takes mm = g + 4*it
        {
            int rr = tid >> 6, g = (tid >> 4) & 3, k = tid & 15;
            float acc = 0.f;
            if (k < K) {
                for (int it = 0; it < 32; ++it) {
                    int mm = g + 4 * it;
                    acc += sAlpha[rr][mm] * sOut[mm * K + k];
                }
            }
            sRed[tid] = acc;
        }
        __syncthreads();
        {
            int rr = tid >> 6, k = tid & 63;
            if (k < K) {
                float tot = bn[(a * H + h) * K + k];
#pragma unroll
                for (int g = 0; g < 4; ++g) tot += sRed[rr * 64 + g * 16 + k];
                float e = tot > 0.f ? tot : __expf(tot) - 1.f;   // elu
                int i2 = itile * 16 + pass * 4 + rr;
                out[(i2 * NATTR + a) * OUTW + outOff + h * K + k] = e;
                if (xh_out != nullptr)
                    xh_out[((size_t)a * N + i2) * F + h * K + k] = e;
            }
        }
        __syncthreads();
    }
}

// ---------------------------------------------------------------------------
extern "C" void kernel_launch(void* const* d_in, const int* in_sizes, int n_in,
                              void* d_out, int out_size, void* d_ws, size_t ws_size,
                              hipStream_t stream) {
    const float* X    = (const float*)d_in[0];
    const float* A    = (const float*)d_in[1];
    const float* E    = (const float*)d_in[2];
    const float* adj  = (const float*)d_in[3];
    const float* Wn0  = (const float*)d_in[4];
    const float* bn0  = (const float*)d_in[5];
    const float* an0s = (const float*)d_in[6];
    const float* an0n = (const float*)d_in[7];
    const float* Wn1  = (const float*)d_in[8];
    const float* bn1  = (const float*)d_in[9];
    const float* an1s = (const float*)d_in[10];
    const float* an1n = (const float*)d_in[11];
    const float* We0  = (const float*)d_in[12];
    const float* be0  = (const float*)d_in[13];
    const float* We1  = (const float*)d_in[14];
    const float* be1  = (const float*)d_in[15];
    const float* Wct0 = (const float*)d_in[16];
    const float* bct0 = (const float*)d_in[17];
    const float* Wct1 = (const float*)d_in[18];
    const float* bct1 = (const float*)d_in[19];
    const float* ae0s = (const float*)d_in[20];
    const float* ae0n = (const float*)d_in[21];
    const float* ae1s = (const float*)d_in[22];
    const float* ae1n = (const float*)d_in[23];
    float* out = (float*)d_out;

    float* p = (float*)d_ws;
    float* feat  = p; p += NATTR * H * N * 16;
    float* aself = p; p += NATTR * H * N;
    float* fe0   = p; p += H * M * 4;
    float* ae0e  = p; p += H * M;
    float* fe1   = p; p += H * M * 2;
    float* ae1e  = p; p += H * M;
    float* part  = p; p += (size_t)NATTR * H * N * MSL * 8;
    float* wvec  = p; p += NATTR * H * F;
    float* einfo = p; p += NATTR * N * N;
    float* xh    = p; p += NATTR * N * F;

    k_front<<<dim3(281), dim3(256), 0, stream>>>(
        X, E, We0, ae0n, We1, ae1n, Wn0, ae0s, Wn1, ae1s,
        out, fe0, ae0e, fe1, ae1e, feat, aself, wvec);

    // ---- layer 0 ----
    k_edge_attn<4, false><<<dim3((H / HG) * 8 * MSL), dim3(256), 0, stream>>>(
        fe0, ae0e, aself, nullptr, nullptr, adj, part);
    k_tail<16, 4, false><<<dim3(192), dim3(256), 0, stream>>>(
        feat, nullptr, nullptr, part, be0, Wct0, bct0, an0s, an0n,
        E, A, bn0, out, F, xh, einfo);

    // ---- layer 1 ----
    k_edge_attn<2, true><<<dim3((H / HG) * 8 * MSL), dim3(256), 0, stream>>>(
        fe1, ae1e, nullptr, xh, wvec, adj, part);
    k_tail<8, 2, true><<<dim3(192), dim3(256), 0, stream>>>(
        nullptr, xh, Wn1, part, be1, Wct1, bct1, an1s, an1n,
        einfo, A, bn1, out, F + 128, nullptr, nullptr);
}